// Round 3
// baseline (125.924 us; speedup 1.0000x reference)
//
#include <hip/hip_runtime.h>

// DecoderLayer: out[k,n,m] = tanh(sum_p w[k,p]*prev[idx[k,p],n,m] + b[k]),
// gated by (#active parents >= 12).  M=2048, K=4096, NN=4096 (64x64), P=16.
//
// One fused kernel. Block = 256 threads, owns POS_TILE=8 positions; stages
// prev[:, pos0:pos0+8] (64 KiB, XOR-swizzled) in LDS -> 2 blocks/CU resident.
// Each thread then processes 16 nodes (one per kk iter) x 8 positions,
// gathering 16 parent rows from LDS (2x ds_read_b128 each).

#define M_ROWS   2048
#define K_NODES  4096
#define NN       4096
#define POS_TILE 8
#define LDS_BYTES (M_ROWS * POS_TILE * 4)   // 65536 B
#define OUT_ELEMS (K_NODES * NN)
#define ACTIVE_THRESHOLD 12

typedef float f32x4 __attribute__((ext_vector_type(4)));

__device__ __forceinline__ float fast_tanh(float x) {
  float ax = __builtin_fabsf(x);
  float e  = __expf(-2.0f * ax);
  float r  = (1.0f - e) * __builtin_amdgcn_rcpf(1.0f + e);
  return __builtin_copysignf(r, x);
}

// LDS layout: row r, 16B-half h stored at word offset r*8 + ((h ^ ((r>>2)&1))<<2).
// Segment-start banks are uniform over all 8 16B slots for random r -> same
// conflict stats as a padded stride, but dense 64 KiB (2 blocks/CU).

__global__ __launch_bounds__(256, 2) void decoder_kernel(
    const float* __restrict__ prev, const unsigned int* __restrict__ isact,
    const int* __restrict__ pidx, const float* __restrict__ w,
    const float* __restrict__ b, float* __restrict__ out,
    float* __restrict__ outact) {
  extern __shared__ float xs[];
  __shared__ int mode_sh;
  const int tid = threadIdx.x;
  if (tid == 0) mode_sh = 0;
  __syncthreads();

  // Detect isact marshaling: scanning first 2048 BYTES as 512 words; any word
  // value >1 implies packed bytes (e.g. 0x00010100). Safe in both modes.
  int bad = 0;
  for (int i = tid; i < 512; i += 256) bad |= (isact[i] > 1u);
  if (bad) atomicOr(&mode_sh, 1);

  // XCD-chunked swizzle: adjacent pos-tiles (sharing 64B lines) land on the
  // same XCD, concurrently resident -> L2 merges half-line writes.
  int bid  = blockIdx.x;                         // 0..511
  int tile = (bid & 7) * (NN / POS_TILE / 8) + (bid >> 3);
  int pos0 = tile * POS_TILE;

  // ---- stage prev[:, pos0:pos0+8] into swizzled LDS ----
  #pragma unroll
  for (int it = 0; it < (M_ROWS * 2) / 256; ++it) {   // 16 iters
    int linear = (it << 8) + tid;                     // 0..4095
    int row  = linear >> 1;
    int half = linear & 1;
    int s    = (row >> 2) & 1;
    float4 v = *(const float4*)(prev + row * NN + pos0 + (half << 2));
    *(float4*)(&xs[(row << 3) + ((half ^ s) << 2)]) = v;
  }
  __syncthreads();

  const int shift = mode_sh ? 0 : 2;   // byte index scale into isact
  const unsigned char* actb = (const unsigned char*)isact;  // LSB of 0/1 word == value

  for (int kk = 0; kk < K_NODES / 256; ++kk) {        // 16 iters
    int k = (kk << 8) + tid;
    const int4*   ip  = (const int4*)(pidx + (k << 4));
    const float4* wp4 = (const float4*)(w + (k << 4));
    int4   ia = ip[0],  ib = ip[1],  ic = ip[2],  id4 = ip[3];
    float4 wa = wp4[0], wb = wp4[1], wc = wp4[2], wd = wp4[3];
    int ids[16] = {ia.x, ia.y, ia.z, ia.w, ib.x, ib.y, ib.z, ib.w,
                   ic.x, ic.y, ic.z, ic.w, id4.x, id4.y, id4.z, id4.w};
    float ws[16] = {wa.x, wa.y, wa.z, wa.w, wb.x, wb.y, wb.z, wb.w,
                    wc.x, wc.y, wc.z, wc.w, wd.x, wd.y, wd.z, wd.w};
    float bk = b[k];
    float acc[8];
    #pragma unroll
    for (int j = 0; j < 8; ++j) acc[j] = bk;

    int cnt = 0;
    #pragma unroll
    for (int p = 0; p < 16; ++p) {
      int id = ids[p];
      cnt += (actb[id << shift] != 0);               // L1-resident gate table
      int s = (id >> 2) & 1;
      const float* rp = &xs[id << 3];
      float4 lo = *(const float4*)(rp + (s << 2));          // ds_read_b128
      float4 hi = *(const float4*)(rp + ((s ^ 1) << 2));    // ds_read_b128
      float wpv = ws[p];
      acc[0] += wpv * lo.x; acc[1] += wpv * lo.y;
      acc[2] += wpv * lo.z; acc[3] += wpv * lo.w;
      acc[4] += wpv * hi.x; acc[5] += wpv * hi.y;
      acc[6] += wpv * hi.z; acc[7] += wpv * hi.w;
    }

    float g = (cnt >= ACTIVE_THRESHOLD) ? 1.0f : 0.0f;
    f32x4 o0, o1;
    o0.x = fast_tanh(acc[0]) * g; o0.y = fast_tanh(acc[1]) * g;
    o0.z = fast_tanh(acc[2]) * g; o0.w = fast_tanh(acc[3]) * g;
    o1.x = fast_tanh(acc[4]) * g; o1.y = fast_tanh(acc[5]) * g;
    o1.z = fast_tanh(acc[6]) * g; o1.w = fast_tanh(acc[7]) * g;

    float* op = out + (size_t)k * NN + pos0;
    *(f32x4*)op       = o0;        // regular stores: let L2 merge 64B lines
    *(f32x4*)(op + 4) = o1;

    if (bid == 0) outact[k] = g;   // one block owns the out_active vector
  }
}

extern "C" void kernel_launch(void* const* d_in, const int* in_sizes, int n_in,
                              void* d_out, int out_size, void* d_ws, size_t ws_size,
                              hipStream_t stream) {
  const float* prev  = (const float*)d_in[0];
  const void*  isact = d_in[1];
  const int*   pidx  = (const int*)d_in[2];
  const float* w     = (const float*)d_in[3];
  const float* b     = (const float*)d_in[4];
  float* out    = (float*)d_out;
  float* outact = out + OUT_ELEMS;

  (void)hipFuncSetAttribute((const void*)decoder_kernel,
                            hipFuncAttributeMaxDynamicSharedMemorySize, LDS_BYTES);

  decoder_kernel<<<NN / POS_TILE, 256, LDS_BYTES, stream>>>(
      prev, (const unsigned int*)isact, pidx, w, b, out, outact);
}

// Round 4
// 117.109 us; speedup vs baseline: 1.0753x; 1.0753x over previous
//
#include <hip/hip_runtime.h>

// DecoderLayer: out[k,n,m] = tanh(sum_p w[k,p]*prev[idx[k,p],n,m] + b[k]),
// gated by (#active parents >= 12).  M=2048, K=4096, NN=4096 (64x64), P=16.
//
// act_kernel: per-node gate (0/1 float) once for the whole grid (off hot path).
// decoder:    block owns POS_TILE=4 positions; stages prev[:,pos0:pos0+4]
//             (32 KiB, natural [2048][4] layout -> rows uniform over the 8
//             bank-groups, one ds_read_b128 per parent). 16 named x-registers
//             per node force deep lgkmcnt pipelining; 2 acc chains.

#define M_ROWS   2048
#define K_NODES  4096
#define NN       4096
#define POS_TILE 4
#define LDS_BYTES (M_ROWS * POS_TILE * 4)   // 32768 B -> up to 5 blocks/CU
#define OUT_ELEMS (K_NODES * NN)
#define ACTIVE_THRESHOLD 12

typedef float f32x4 __attribute__((ext_vector_type(4)));

__device__ __forceinline__ float fast_tanh(float x) {
  float ax = __builtin_fabsf(x);
  float e  = __expf(-2.0f * ax);
  float r  = (1.0f - e) * __builtin_amdgcn_rcpf(1.0f + e);
  return __builtin_copysignf(r, x);
}

// Gate precompute. Runtime-detects isact marshaling (int32 words vs packed
// bytes): any 32-bit word >1 in the first 2048 bytes implies byte packing.
__global__ __launch_bounds__(256) void act_kernel(
    const int* __restrict__ pidx, const unsigned int* __restrict__ isact,
    float* __restrict__ outact) {
  __shared__ int mode_sh;
  if (threadIdx.x == 0) mode_sh = 0;
  __syncthreads();
  int bad = 0;
  for (int i = threadIdx.x; i < 512; i += 256) bad |= (isact[i] > 1u);
  if (bad) atomicOr(&mode_sh, 1);
  __syncthreads();
  const int shift = mode_sh ? 0 : 2;   // byte index scale (LSB of 0/1 word == value)
  const unsigned char* actb = (const unsigned char*)isact;

  int k = blockIdx.x * 256 + threadIdx.x;
  const int4* ip = (const int4*)(pidx + k * 16);
  int4 ia = ip[0], ib = ip[1], ic = ip[2], id4 = ip[3];
  int ids[16] = {ia.x, ia.y, ia.z, ia.w, ib.x, ib.y, ib.z, ib.w,
                 ic.x, ic.y, ic.z, ic.w, id4.x, id4.y, id4.z, id4.w};
  int n = 0;
  #pragma unroll
  for (int p = 0; p < 16; ++p) n += (actb[ids[p] << shift] != 0);
  outact[k] = (n >= ACTIVE_THRESHOLD) ? 1.0f : 0.0f;
}

__global__ __launch_bounds__(256, 4) void decoder_kernel(
    const float* __restrict__ prev, const int* __restrict__ pidx,
    const float* __restrict__ w, const float* __restrict__ b,
    const float* __restrict__ actf, float* __restrict__ out) {
  extern __shared__ float xs[];   // [2048][4]
  const int tid = threadIdx.x;

  // XCD-chunked swizzle: the 4-8 tiles sharing each 64B prev/out line are
  // concurrently resident on the same XCD -> L2 merges partial lines.
  int bid  = blockIdx.x;                                  // 0..1023
  int tile = (bid & 7) * (NN / POS_TILE / 8) + (bid >> 3);
  int pos0 = tile * POS_TILE;

  #pragma unroll
  for (int it = 0; it < 8; ++it) {
    int row = (it << 8) + tid;
    *(f32x4*)(&xs[row << 2]) = *(const f32x4*)(prev + row * NN + pos0);
  }
  __syncthreads();

  for (int kk = 0; kk < K_NODES / 256; ++kk) {            // 16 iters
    int k = (kk << 8) + tid;
    const int4*   ip = (const int4*)(pidx + (k << 4));
    const float4* wp = (const float4*)(w + (k << 4));
    float bk = b[k];
    float g  = actf[k];                                   // 0.0 / 1.0

    int4   ia = ip[0], ib = ip[1];
    float4 wa = wp[0], wb = wp[1];
    // batch 1: 8 independent ds_read_b128
    f32x4 x0 = *(const f32x4*)(&xs[ia.x << 2]);
    f32x4 x1 = *(const f32x4*)(&xs[ia.y << 2]);
    f32x4 x2 = *(const f32x4*)(&xs[ia.z << 2]);
    f32x4 x3 = *(const f32x4*)(&xs[ia.w << 2]);
    f32x4 x4 = *(const f32x4*)(&xs[ib.x << 2]);
    f32x4 x5 = *(const f32x4*)(&xs[ib.y << 2]);
    f32x4 x6 = *(const f32x4*)(&xs[ib.z << 2]);
    f32x4 x7 = *(const f32x4*)(&xs[ib.w << 2]);

    int4   ic = ip[2], id4 = ip[3];
    float4 wc = wp[2], wd = wp[3];
    // batch 2 issued while batch-1 FMAs retire
    f32x4 y0 = *(const f32x4*)(&xs[ic.x  << 2]);
    f32x4 y1 = *(const f32x4*)(&xs[ic.y  << 2]);
    f32x4 y2 = *(const f32x4*)(&xs[ic.z  << 2]);
    f32x4 y3 = *(const f32x4*)(&xs[ic.w  << 2]);
    f32x4 y4 = *(const f32x4*)(&xs[id4.x << 2]);
    f32x4 y5 = *(const f32x4*)(&xs[id4.y << 2]);
    f32x4 y6 = *(const f32x4*)(&xs[id4.z << 2]);
    f32x4 y7 = *(const f32x4*)(&xs[id4.w << 2]);

    f32x4 acc0 = {bk, bk, bk, bk};
    f32x4 acc1 = {0.f, 0.f, 0.f, 0.f};
    acc0 += wa.x * x0;  acc1 += wa.y * x1;
    acc0 += wa.z * x2;  acc1 += wa.w * x3;
    acc0 += wb.x * x4;  acc1 += wb.y * x5;
    acc0 += wb.z * x6;  acc1 += wb.w * x7;
    acc0 += wc.x * y0;  acc1 += wc.y * y1;
    acc0 += wc.z * y2;  acc1 += wc.w * y3;
    acc0 += wd.x * y4;  acc1 += wd.y * y5;
    acc0 += wd.z * y6;  acc1 += wd.w * y7;
    f32x4 acc = acc0 + acc1;

    f32x4 o;
    o.x = fast_tanh(acc.x) * g;
    o.y = fast_tanh(acc.y) * g;
    o.z = fast_tanh(acc.z) * g;
    o.w = fast_tanh(acc.w) * g;
    *(f32x4*)(out + (size_t)k * NN + pos0) = o;   // L2 merges 16B quarters
  }
}

extern "C" void kernel_launch(void* const* d_in, const int* in_sizes, int n_in,
                              void* d_out, int out_size, void* d_ws, size_t ws_size,
                              hipStream_t stream) {
  const float* prev  = (const float*)d_in[0];
  const void*  isact = d_in[1];
  const int*   pidx  = (const int*)d_in[2];
  const float* w     = (const float*)d_in[3];
  const float* b     = (const float*)d_in[4];
  float* out    = (float*)d_out;
  float* outact = out + OUT_ELEMS;

  (void)hipFuncSetAttribute((const void*)decoder_kernel,
                            hipFuncAttributeMaxDynamicSharedMemorySize, LDS_BYTES);

  act_kernel<<<K_NODES / 256, 256, 0, stream>>>(
      pidx, (const unsigned int*)isact, outact);
  decoder_kernel<<<NN / POS_TILE, 256, LDS_BYTES, stream>>>(
      prev, pidx, w, b, outact, out);
}